// Round 1
// baseline (176.126 us; speedup 1.0000x reference)
//
#include <hip/hip_runtime.h>
#include <math.h>

#define NCAT  5
#define BATCH 64
#define ELEMS 196608        // C*H*W = 3*256*256
#define POSB  64            // positions per block (one per lane)
#define NBLK  (ELEMS / POSB) // 3072 blocks
#define TPB   256           // 4 waves; wave w handles batch chunk [16w, 16w+16)
#define CHUNK 16            // batches per wave
#define GRP   8             // batches per pipeline stage
#define EPSV  1e-6f

// d_ws layout: partials[15][NBLK] floats.
// rows 0..4 = per-block cat_scaled_sum, 5..9 = cat_abs_sum, 10..14 = un sums
__global__ __launch_bounds__(TPB) void accum_kernel(
    const float* __restrict__ restored,
    const float* __restrict__ clean,
    const int*   __restrict__ de_id,
    const float* __restrict__ un,
    float*       __restrict__ partials)
{
    __shared__ int   sh_de[BATCH];
    __shared__ float sh_inv[NCAT];
    // combine buffer: [slot][kind*cat][lane] -> lane-contiguous, conflict-free
    __shared__ float sbuf[2][2 * NCAT][POSB];

    const int tid  = threadIdx.x;
    const int lane = tid & 63;
    const int wave = tid >> 6;

    // wave 0: load de_id, ballot-count categories, store 1/safe_count
    if (tid < BATCH) {
        int k = de_id[tid];
        sh_de[tid] = k;
        #pragma unroll
        for (int j = 0; j < NCAT; ++j) {
            unsigned long long m = __ballot(k == j);
            if (tid == j) {
                int c = __popcll(m);
                sh_inv[j] = 1.0f / (float)(c > 0 ? c : 1);
            }
        }
    }
    __syncthreads();

    // each wave: its own 16-batch chunk at this block's 64 positions
    const size_t base = (size_t)(wave * CHUNK) * ELEMS
                      + (size_t)blockIdx.x * POSB + lane;
    const float* rp = restored + base;
    const float* cp = clean + base;
    const float* up = un + base;

    float un_s[NCAT] = {0.f, 0.f, 0.f, 0.f, 0.f};
    float ad_s[NCAT] = {0.f, 0.f, 0.f, 0.f, 0.f};

    // double-buffered register pipeline over the 16-batch chunk
    float ub[2][GRP], cb[2][GRP], rb[2][GRP];

    #pragma unroll
    for (int i = 0; i < GRP; ++i) {
        const size_t off = (size_t)i * ELEMS;
        ub[0][i] = up[off];
        cb[0][i] = cp[off];
        rb[0][i] = rp[off];
    }

    #pragma unroll
    for (int g = 0; g < CHUNK / GRP; ++g) {
        const int cur = g & 1;
        const int nxt = cur ^ 1;
        if (g < CHUNK / GRP - 1) {
            #pragma unroll
            for (int i = 0; i < GRP; ++i) {
                const size_t off = (size_t)((g + 1) * GRP + i) * ELEMS;
                ub[nxt][i] = up[off];
                cb[nxt][i] = cp[off];
                rb[nxt][i] = rp[off];
            }
        }
        #pragma unroll
        for (int i = 0; i < GRP; ++i) {
            float u  = ub[cur][i];
            float ad = fabsf(cb[cur][i] - rb[cur][i]);
            int   k  = sh_de[wave * CHUNK + g * GRP + i];
            #pragma unroll
            for (int j = 0; j < NCAT; ++j) {
                float m = (k == j) ? 1.0f : 0.0f;
                un_s[j] = fmaf(m, u,  un_s[j]);
                ad_s[j] = fmaf(m, ad, ad_s[j]);
            }
        }
    }

    // ---- combine the 4 batch-chunks into wave 0 (2-round LDS tree) ----
    // round 1: waves 2,3 -> slots 0,1 ; waves 0,1 add
    if (wave >= 2) {
        #pragma unroll
        for (int j = 0; j < NCAT; ++j) {
            sbuf[wave - 2][j][lane]        = un_s[j];
            sbuf[wave - 2][NCAT + j][lane] = ad_s[j];
        }
    }
    __syncthreads();
    if (wave < 2) {
        #pragma unroll
        for (int j = 0; j < NCAT; ++j) {
            un_s[j] += sbuf[wave][j][lane];
            ad_s[j] += sbuf[wave][NCAT + j][lane];
        }
    }
    __syncthreads();
    // round 2: wave 1 -> slot 0 ; wave 0 adds
    if (wave == 1) {
        #pragma unroll
        for (int j = 0; j < NCAT; ++j) {
            sbuf[0][j][lane]        = un_s[j];
            sbuf[0][NCAT + j][lane] = ad_s[j];
        }
    }
    __syncthreads();
    if (wave == 0) {
        #pragma unroll
        for (int j = 0; j < NCAT; ++j) {
            un_s[j] += sbuf[0][j][lane];
            ad_s[j] += sbuf[0][NCAT + j][lane];
        }

        // per-position contributions to the 15 accumulators
        float vals[3 * NCAT];
        #pragma unroll
        for (int j = 0; j < NCAT; ++j) {
            float um = fmaf(un_s[j], sh_inv[j], EPSV);   // un_map at this position
            vals[j]            = ad_s[j] / um;
            vals[NCAT + j]     = ad_s[j];
            vals[2 * NCAT + j] = un_s[j];
        }

        // 64-lane butterfly reduction (whole wave 0 active)
        #pragma unroll
        for (int i = 0; i < 3 * NCAT; ++i) {
            float v = vals[i];
            #pragma unroll
            for (int off = 32; off >= 1; off >>= 1)
                v += __shfl_down(v, off, 64);
            vals[i] = v;
        }

        if (lane == 0) {
            #pragma unroll
            for (int i = 0; i < 3 * NCAT; ++i)
                partials[i * NBLK + blockIdx.x] = vals[i];   // row-contiguous
        }
    }
}

// 1 block, 1024 threads: reduce [15][3072] partials + final 21-output math
__global__ __launch_bounds__(1024) void epilogue_kernel(
    const int*   __restrict__ de_id,
    const float* __restrict__ partials,
    float*       __restrict__ out)
{
    __shared__ int   sh_cnt[NCAT];
    __shared__ float sh_acc[3 * NCAT];

    const int tid  = threadIdx.x;
    const int lane = tid & 63;
    const int row  = tid >> 6;          // one wave per partials row, rows 0..14

    if (tid < 64) {
        int k = de_id[tid];
        #pragma unroll
        for (int j = 0; j < NCAT; ++j) {
            unsigned long long m = __ballot(k == j);
            if (tid == j) sh_cnt[j] = __popcll(m);
        }
    }

    if (row < 3 * NCAT) {
        float v = 0.f;
        #pragma unroll 8
        for (int k = 0; k < NBLK / 64; ++k)          // 48 coalesced passes
            v += partials[row * NBLK + lane + (k << 6)];
        #pragma unroll
        for (int off = 32; off >= 1; off >>= 1)
            v += __shfl_down(v, off, 64);
        if (lane == 0) sh_acc[row] = v;
    }
    __syncthreads();

    if (tid == 0) {
        const float Ef = (float)ELEMS;
        float cum_s = 0.f;
        long  cum_c = 0;
        float total = 0.f;
        int   num   = 0;

        float cat_losses[NCAT], old_loss[NCAT], bn[NCAT], unc_l1[NCAT];

        for (int j = 0; j < NCAT; ++j) {
            cum_s += sh_acc[j];
            cum_c += sh_cnt[j];
            float cum_elems = (float)cum_c * Ef;
            float cum_l1    = cum_s / fmaxf(cum_elems, 1.0f);

            bool  ne   = sh_cnt[j] > 0;
            float safe = (float)(ne ? sh_cnt[j] : 1);

            old_loss[j]  = ne ? sh_acc[NCAT + j] / (safe * Ef) : 0.f;
            float un_num = sh_acc[2 * NCAT + j] / (safe * Ef) + EPSV;
            bn[j]        = ne ? 2.0f * logf(un_num) : 0.f;
            unc_l1[j]    = ne ? cum_l1 : 0.f;
            cat_losses[j] = unc_l1[j] + bn[j];
            total += cat_losses[j];
            num   += ne ? 1 : 0;
        }
        total /= (float)num;

        out[0] = total;
        for (int j = 0; j < NCAT; ++j) {
            out[1 + j]  = cat_losses[j];
            out[6 + j]  = old_loss[j];
            out[11 + j] = bn[j];
            out[16 + j] = unc_l1[j];
        }
    }
}

extern "C" void kernel_launch(void* const* d_in, const int* in_sizes, int n_in,
                              void* d_out, int out_size, void* d_ws, size_t ws_size,
                              hipStream_t stream) {
    (void)in_sizes; (void)n_in; (void)out_size; (void)ws_size;
    const float* restored = (const float*)d_in[0];
    const float* clean    = (const float*)d_in[1];
    const int*   de_id    = (const int*)d_in[2];
    const float* un       = (const float*)d_in[3];
    float* out      = (float*)d_out;
    float* partials = (float*)d_ws;   // [15][NBLK] floats — fully overwritten

    accum_kernel<<<NBLK, TPB, 0, stream>>>(restored, clean, de_id, un, partials);
    epilogue_kernel<<<1, 1024, 0, stream>>>(de_id, partials, out);
}

// Round 2
// 173.613 us; speedup vs baseline: 1.0145x; 1.0145x over previous
//
#include <hip/hip_runtime.h>
#include <math.h>

#define NCAT  5
#define BATCH 64
#define ELEMS 196608        // C*H*W = 3*256*256
#define POSB  256           // positions per block = 64 lanes * 4 (float4)
#define NBLK  (ELEMS / POSB) // 768 blocks
#define TPB   256           // 4 waves; wave w handles batch chunk [16w, 16w+16)
#define CHUNK 16            // batches per wave
#define GRP   4             // batches per pipeline stage (12 float4 loads/stage)
#define EPSV  1e-6f

// d_ws layout: partials[15][NBLK] floats.
// rows 0..4 = per-block cat_scaled_sum, 5..9 = cat_abs_sum, 10..14 = un sums
__global__ __launch_bounds__(TPB, 3) void accum_kernel(
    const float* __restrict__ restored,
    const float* __restrict__ clean,
    const int*   __restrict__ de_id,
    const float* __restrict__ un,
    float*       __restrict__ partials)
{
    __shared__ int    sh_de[BATCH];
    __shared__ float  sh_inv[NCAT];
    // combine buffer: [slot][kind*cat][lane] of float4 (4 positions per lane)
    __shared__ float4 sbuf[2][2 * NCAT][64];

    const int tid  = threadIdx.x;
    const int lane = tid & 63;
    const int wave = tid >> 6;

    // wave 0: load de_id, ballot-count categories, store 1/safe_count
    if (tid < BATCH) {
        int k = de_id[tid];
        sh_de[tid] = k;
        #pragma unroll
        for (int j = 0; j < NCAT; ++j) {
            unsigned long long m = __ballot(k == j);
            if (tid == j) {
                int c = __popcll(m);
                sh_inv[j] = 1.0f / (float)(c > 0 ? c : 1);
            }
        }
    }
    __syncthreads();

    // each wave: its own 16-batch chunk; lane owns 4 consecutive positions
    const size_t base = (size_t)(wave * CHUNK) * ELEMS
                      + (size_t)blockIdx.x * POSB + (size_t)lane * 4;
    const float4* rp = (const float4*)(restored + base);
    const float4* cp = (const float4*)(clean + base);
    const float4* up = (const float4*)(un + base);
    const size_t STR4 = ELEMS / 4;   // per-batch stride in float4 units

    // accumulators: [cat][position-in-lane]
    float acc_un[NCAT][4];
    float acc_ad[NCAT][4];
    #pragma unroll
    for (int j = 0; j < NCAT; ++j)
        #pragma unroll
        for (int ii = 0; ii < 4; ++ii) { acc_un[j][ii] = 0.f; acc_ad[j][ii] = 0.f; }

    // double-buffered register pipeline: GRP batches (12 float4 loads) / stage
    float4 ub[2][GRP], cb[2][GRP], rb[2][GRP];

    #pragma unroll
    for (int i = 0; i < GRP; ++i) {
        const size_t off = (size_t)i * STR4;
        ub[0][i] = up[off];
        cb[0][i] = cp[off];
        rb[0][i] = rp[off];
    }

    #pragma unroll
    for (int g = 0; g < CHUNK / GRP; ++g) {
        const int cur = g & 1;
        const int nxt = cur ^ 1;
        if (g < CHUNK / GRP - 1) {
            #pragma unroll
            for (int i = 0; i < GRP; ++i) {
                const size_t off = (size_t)((g + 1) * GRP + i) * STR4;
                ub[nxt][i] = up[off];
                cb[nxt][i] = cp[off];
                rb[nxt][i] = rp[off];
            }
        }
        #pragma unroll
        for (int i = 0; i < GRP; ++i) {
            float4 u = ub[cur][i];
            float4 c = cb[cur][i];
            float4 r = rb[cur][i];
            float ad0 = fabsf(c.x - r.x);
            float ad1 = fabsf(c.y - r.y);
            float ad2 = fabsf(c.z - r.z);
            float ad3 = fabsf(c.w - r.w);
            int   k   = sh_de[wave * CHUNK + g * GRP + i];
            #pragma unroll
            for (int j = 0; j < NCAT; ++j) {
                float m = (k == j) ? 1.0f : 0.0f;
                acc_un[j][0] = fmaf(m, u.x, acc_un[j][0]);
                acc_un[j][1] = fmaf(m, u.y, acc_un[j][1]);
                acc_un[j][2] = fmaf(m, u.z, acc_un[j][2]);
                acc_un[j][3] = fmaf(m, u.w, acc_un[j][3]);
                acc_ad[j][0] = fmaf(m, ad0, acc_ad[j][0]);
                acc_ad[j][1] = fmaf(m, ad1, acc_ad[j][1]);
                acc_ad[j][2] = fmaf(m, ad2, acc_ad[j][2]);
                acc_ad[j][3] = fmaf(m, ad3, acc_ad[j][3]);
            }
        }
    }

    // ---- combine the 4 batch-chunks into wave 0 (2-round LDS tree) ----
    // round 1: waves 2,3 -> slots 0,1 ; waves 0,1 add
    if (wave >= 2) {
        #pragma unroll
        for (int j = 0; j < NCAT; ++j) {
            sbuf[wave - 2][j][lane] =
                make_float4(acc_un[j][0], acc_un[j][1], acc_un[j][2], acc_un[j][3]);
            sbuf[wave - 2][NCAT + j][lane] =
                make_float4(acc_ad[j][0], acc_ad[j][1], acc_ad[j][2], acc_ad[j][3]);
        }
    }
    __syncthreads();
    if (wave < 2) {
        #pragma unroll
        for (int j = 0; j < NCAT; ++j) {
            float4 tu = sbuf[wave][j][lane];
            float4 ta = sbuf[wave][NCAT + j][lane];
            acc_un[j][0] += tu.x; acc_un[j][1] += tu.y;
            acc_un[j][2] += tu.z; acc_un[j][3] += tu.w;
            acc_ad[j][0] += ta.x; acc_ad[j][1] += ta.y;
            acc_ad[j][2] += ta.z; acc_ad[j][3] += ta.w;
        }
    }
    __syncthreads();
    // round 2: wave 1 -> slot 0 ; wave 0 adds
    if (wave == 1) {
        #pragma unroll
        for (int j = 0; j < NCAT; ++j) {
            sbuf[0][j][lane] =
                make_float4(acc_un[j][0], acc_un[j][1], acc_un[j][2], acc_un[j][3]);
            sbuf[0][NCAT + j][lane] =
                make_float4(acc_ad[j][0], acc_ad[j][1], acc_ad[j][2], acc_ad[j][3]);
        }
    }
    __syncthreads();
    if (wave == 0) {
        #pragma unroll
        for (int j = 0; j < NCAT; ++j) {
            float4 tu = sbuf[0][j][lane];
            float4 ta = sbuf[0][NCAT + j][lane];
            acc_un[j][0] += tu.x; acc_un[j][1] += tu.y;
            acc_un[j][2] += tu.z; acc_un[j][3] += tu.w;
            acc_ad[j][0] += ta.x; acc_ad[j][1] += ta.y;
            acc_ad[j][2] += ta.z; acc_ad[j][3] += ta.w;
        }

        // per-position nonlinear step, summed over this lane's 4 positions
        float vals[3 * NCAT];
        #pragma unroll
        for (int j = 0; j < NCAT; ++j) {
            float s_sc = 0.f, s_ad = 0.f, s_un = 0.f;
            #pragma unroll
            for (int ii = 0; ii < 4; ++ii) {
                float um = fmaf(acc_un[j][ii], sh_inv[j], EPSV);  // un_map
                s_sc += acc_ad[j][ii] / um;
                s_ad += acc_ad[j][ii];
                s_un += acc_un[j][ii];
            }
            vals[j]            = s_sc;
            vals[NCAT + j]     = s_ad;
            vals[2 * NCAT + j] = s_un;
        }

        // 64-lane butterfly reduction
        #pragma unroll
        for (int i = 0; i < 3 * NCAT; ++i) {
            float v = vals[i];
            #pragma unroll
            for (int off = 32; off >= 1; off >>= 1)
                v += __shfl_down(v, off, 64);
            vals[i] = v;
        }

        if (lane == 0) {
            #pragma unroll
            for (int i = 0; i < 3 * NCAT; ++i)
                partials[i * NBLK + blockIdx.x] = vals[i];   // row-contiguous
        }
    }
}

// 1 block, 256 threads: reduce [15][768] partials + final 21-output math
__global__ __launch_bounds__(256) void epilogue_kernel(
    const int*   __restrict__ de_id,
    const float* __restrict__ partials,
    float*       __restrict__ out)
{
    __shared__ int   sh_cnt[NCAT];
    __shared__ float sh_acc[3 * NCAT];

    const int tid = threadIdx.x;

    if (tid < 64) {
        int k = de_id[tid];
        #pragma unroll
        for (int j = 0; j < NCAT; ++j) {
            unsigned long long m = __ballot(k == j);
            if (tid == j) sh_cnt[j] = __popcll(m);
        }
    }

    if (tid < 240) {
        const int row    = tid >> 4;
        const int lane16 = tid & 15;
        float v = 0.f;
        #pragma unroll 4
        for (int k = 0; k < NBLK / 16; ++k)
            v += partials[row * NBLK + lane16 + (k << 4)];
        v += __shfl_down(v, 8, 16);
        v += __shfl_down(v, 4, 16);
        v += __shfl_down(v, 2, 16);
        v += __shfl_down(v, 1, 16);
        if (lane16 == 0) sh_acc[row] = v;
    }
    __syncthreads();

    if (tid == 0) {
        const float Ef = (float)ELEMS;
        float cum_s = 0.f;
        long  cum_c = 0;
        float total = 0.f;
        int   num   = 0;

        float cat_losses[NCAT], old_loss[NCAT], bn[NCAT], unc_l1[NCAT];

        for (int j = 0; j < NCAT; ++j) {
            cum_s += sh_acc[j];
            cum_c += sh_cnt[j];
            float cum_elems = (float)cum_c * Ef;
            float cum_l1    = cum_s / fmaxf(cum_elems, 1.0f);

            bool  ne   = sh_cnt[j] > 0;
            float safe = (float)(ne ? sh_cnt[j] : 1);

            old_loss[j]  = ne ? sh_acc[NCAT + j] / (safe * Ef) : 0.f;
            float un_num = sh_acc[2 * NCAT + j] / (safe * Ef) + EPSV;
            bn[j]        = ne ? 2.0f * logf(un_num) : 0.f;
            unc_l1[j]    = ne ? cum_l1 : 0.f;
            cat_losses[j] = unc_l1[j] + bn[j];
            total += cat_losses[j];
            num   += ne ? 1 : 0;
        }
        total /= (float)num;

        out[0] = total;
        for (int j = 0; j < NCAT; ++j) {
            out[1 + j]  = cat_losses[j];
            out[6 + j]  = old_loss[j];
            out[11 + j] = bn[j];
            out[16 + j] = unc_l1[j];
        }
    }
}

extern "C" void kernel_launch(void* const* d_in, const int* in_sizes, int n_in,
                              void* d_out, int out_size, void* d_ws, size_t ws_size,
                              hipStream_t stream) {
    (void)in_sizes; (void)n_in; (void)out_size; (void)ws_size;
    const float* restored = (const float*)d_in[0];
    const float* clean    = (const float*)d_in[1];
    const int*   de_id    = (const int*)d_in[2];
    const float* un       = (const float*)d_in[3];
    float* out      = (float*)d_out;
    float* partials = (float*)d_ws;   // [15][NBLK] — fully overwritten, no init needed

    accum_kernel<<<NBLK, TPB, 0, stream>>>(restored, clean, de_id, un, partials);
    epilogue_kernel<<<1, 256, 0, stream>>>(de_id, partials, out);
}